// Round 8
// baseline (184.078 us; speedup 1.0000x reference)
//
#include <hip/hip_runtime.h>

#define IN_CH 64
#define HID   16
#define OUTC  8

typedef _Float16 half2_t __attribute__((ext_vector_type(2)));
typedef _Float16 half4_t __attribute__((ext_vector_type(4)));

// ---------------------------------------------------------------------------
// Workspace (~7.9 MB of the ~256 MB ws):
//   y1h : (N+1)*16 f16   row N = zeros (sentinel row for padded CSR slots)
//   y2h : (N+1)*8  f16   row N = zeros
//   r1  : N*16 f32       x @ W1r^T + b1
//   off : N i32          PADDED exclusive starts (immutable, multiples of 4)
//   cnt : N i32          true in-degrees            (memset 0, with cur)
//   cur : N i32          fill cursors               (memset 0, with cnt)
//   bsum: 256 i32        per-scan-block padded sums
//   adj : (E + 4N) u16   compact padded CSR; bucket n = [off[n], off[n]+pad4(cnt[n]));
//                        pad slots hold sentinel id N (-> zero feature row).
//                        All buckets 4-slot (8 B) aligned => ushort4 loads.
// Compact (1.7 MB) vs 256-slot bins (25.6 MB): random 2 B scatter stores dirty
// ~26k lines instead of ~700k -> writeback 44.7 MB -> ~12 MB (round-7 lesson).
// ---------------------------------------------------------------------------

// ---- K1: layer-1 dual projection, no atomics (round-7 version) ------------
__global__ __launch_bounds__(256) void xform1(
    const float* __restrict__ x,
    const float* __restrict__ W1l,
    const float* __restrict__ W1r,
    const float* __restrict__ b1,
    _Float16* __restrict__ y1h,
    float* __restrict__ r1,
    int n_nodes)
{
    __shared__ __align__(16) float sWl[HID * 68];   // [c][k] pad 68
    __shared__ __align__(16) float sWr[HID * 68];
    __shared__ __align__(16) float sx[16 * 68];     // staged x rows
    __shared__ float sb1[HID];

    int tid = threadIdx.x;
    for (int i = tid; i < HID * IN_CH; i += 256) {
        int c = i >> 6, k = i & 63;                 // W1* is [HID][IN_CH]
        sWl[c * 68 + k] = W1l[i];
        sWr[c * 68 + k] = W1r[i];
    }
    if (tid < HID) sb1[tid] = b1[tid];

    int nl   = tid >> 4;
    int c    = tid & 15;
    int node = blockIdx.x * 16 + nl;

    if (node < n_nodes)
        *(float4*)&sx[nl * 68 + c * 4] =
            *(const float4*)&x[(size_t)node * IN_CH + c * 4];
    __syncthreads();

    if (node >= n_nodes) {
        if (node == n_nodes)
            y1h[(size_t)node * HID + c] = (_Float16)0.f;   // sentinel row
        return;
    }

    float accL = 0.f, accR = 0.f;
#pragma unroll
    for (int k4 = 0; k4 < 16; ++k4) {
        float4 xv = *(const float4*)&sx [nl * 68 + k4 * 4];
        float4 wl = *(const float4*)&sWl[c  * 68 + k4 * 4];
        float4 wr = *(const float4*)&sWr[c  * 68 + k4 * 4];
        accL = fmaf(xv.x, wl.x, accL); accL = fmaf(xv.y, wl.y, accL);
        accL = fmaf(xv.z, wl.z, accL); accL = fmaf(xv.w, wl.w, accL);
        accR = fmaf(xv.x, wr.x, accR); accR = fmaf(xv.y, wr.y, accR);
        accR = fmaf(xv.z, wr.z, accR); accR = fmaf(xv.w, wr.w, accR);
    }
    y1h[(size_t)node * HID + c] = (_Float16)accL;
    r1 [(size_t)node * HID + c] = accR + sb1[c];
}

// ---- K2: degree count (standalone: no barrier after the atomic) -----------
__global__ __launch_bounds__(256) void count_deg(
    const int* __restrict__ edst, int* __restrict__ cnt, int n_edges)
{
    int e = blockIdx.x * 256 + threadIdx.x;
    if (e < n_edges) atomicAdd(&cnt[edst[e]], 1);
}

// ---- K3: per-block partial sums of PADDED degrees -------------------------
__global__ __launch_bounds__(256) void scan_partials(
    const int* __restrict__ cnt, int* __restrict__ bsum, int n)
{
    __shared__ int red[256];
    int t = threadIdx.x;
    int i = blockIdx.x * 256 + t;
    red[t] = (i < n) ? ((cnt[i] + 3) & ~3) : 0;
    __syncthreads();
    for (int s = 128; s > 0; s >>= 1) {
        if (t < s) red[t] += red[t + s];
        __syncthreads();
    }
    if (t == 0) bsum[blockIdx.x] = red[0];
}

// ---- K4: top scan + padded-start scatter + sentinel pad fill --------------
// requires gridDim <= 256
__global__ __launch_bounds__(256) void scan_scatter(
    const int* __restrict__ cnt, const int* __restrict__ bsum,
    int* __restrict__ off, unsigned short* __restrict__ adj,
    int n, int nb, int sentinel)
{
    __shared__ int top[256];
    __shared__ int loc[256];
    int t = threadIdx.x;
    int i = blockIdx.x * 256 + t;
    int cv  = (i < n) ? cnt[i] : 0;
    int v   = (cv + 3) & ~3;                 // padded size
    int bv  = (t < nb) ? bsum[t] : 0;
    loc[t] = v;
    top[t] = bv;
    __syncthreads();
    for (int o = 1; o < 256; o <<= 1) {
        int al = (t >= o) ? loc[t - o] : 0;
        int at = (t >= o) ? top[t - o] : 0;
        __syncthreads();
        loc[t] += al;
        top[t] += at;
        __syncthreads();
    }
    if (i < n) {
        int blk_excl = (blockIdx.x == 0) ? 0 : top[blockIdx.x - 1];
        int start = blk_excl + loc[t] - v;   // padded exclusive start (mult of 4)
        off[i] = start;
        for (int g = cv; g < v; ++g)         // 0..3 sentinel pad slots
            adj[start + g] = (unsigned short)sentinel;
    }
}

// ---- K5: compact bucket fill (off immutable; cur[] cursors) ---------------
__global__ __launch_bounds__(256) void fill_adj(
    const int* __restrict__ esrc, const int* __restrict__ edst,
    const int* __restrict__ off, int* __restrict__ cur,
    unsigned short* __restrict__ adj, int n_edges)
{
    int e = blockIdx.x * 256 + threadIdx.x;
    if (e >= n_edges) return;
    int d = edst[e];
    int pos = off[d] + atomicAdd(&cur[d], 1);
    adj[pos] = (unsigned short)esrc[e];
}

// ---------------------------------------------------------------------------
// K6: fused gather + layer-2. 4 threads/node (q = channel quad), 64 nodes/blk.
// ---------------------------------------------------------------------------
__global__ __launch_bounds__(256) void fused_gather(
    const float* __restrict__ r1,
    const _Float16* __restrict__ y1h,
    const int*   __restrict__ off,
    const int*   __restrict__ cnt,
    const unsigned short* __restrict__ adj,
    const float* __restrict__ W2l, const float* __restrict__ W2r,
    const float* __restrict__ b2,
    _Float16* __restrict__ y2h, float* __restrict__ r2out,
    int n_nodes)
{
    __shared__ float sW2l[HID * OUTC];              // [k][o]
    __shared__ float sW2r[HID * OUTC];
    __shared__ float sb2[OUTC];
    __shared__ float sh[64 * 17];

    int tid = threadIdx.x;
    for (int i = tid; i < HID * OUTC; i += 256) {
        int o = i >> 4, k = i & 15;   // W2* is [OUTC][HID]
        sW2l[k * OUTC + o] = W2l[i];
        sW2r[k * OUTC + o] = W2r[i];
    }
    if (tid < OUTC) sb2[tid] = b2[tid];

    int nl   = tid >> 2;
    int q    = tid & 3;
    int node = blockIdx.x * 64 + nl;
    bool real = node < n_nodes;

    const half2_t k10 = {(_Float16)1.f, (_Float16)0.f};
    const half2_t k01 = {(_Float16)0.f, (_Float16)1.f};

    if (real) {
        int start = off[node];
        int deg   = cnt[node];
        int iters = (deg + 3) >> 2;
        float s0 = 0.f, s1 = 0.f, s2 = 0.f, s3 = 0.f;
        const _Float16* yq = y1h + q * 4;
        const ushort4* ap = (const ushort4*)(adj + start);
        for (int it = 0; it < iters; ++it) {
            ushort4 s = ap[it];
            half4_t v0 = *(const half4_t*)(yq + (size_t)s.x * HID);
            half4_t v1 = *(const half4_t*)(yq + (size_t)s.y * HID);
            half4_t v2 = *(const half4_t*)(yq + (size_t)s.z * HID);
            half4_t v3 = *(const half4_t*)(yq + (size_t)s.w * HID);
            half2_t v0l = {v0.x, v0.y}, v0h = {v0.z, v0.w};
            half2_t v1l = {v1.x, v1.y}, v1h = {v1.z, v1.w};
            half2_t v2l = {v2.x, v2.y}, v2h = {v2.z, v2.w};
            half2_t v3l = {v3.x, v3.y}, v3h = {v3.z, v3.w};
            s0 = __builtin_amdgcn_fdot2(v0l, k10, s0, false);
            s1 = __builtin_amdgcn_fdot2(v0l, k01, s1, false);
            s2 = __builtin_amdgcn_fdot2(v0h, k10, s2, false);
            s3 = __builtin_amdgcn_fdot2(v0h, k01, s3, false);
            s0 = __builtin_amdgcn_fdot2(v1l, k10, s0, false);
            s1 = __builtin_amdgcn_fdot2(v1l, k01, s1, false);
            s2 = __builtin_amdgcn_fdot2(v1h, k10, s2, false);
            s3 = __builtin_amdgcn_fdot2(v1h, k01, s3, false);
            s0 = __builtin_amdgcn_fdot2(v2l, k10, s0, false);
            s1 = __builtin_amdgcn_fdot2(v2l, k01, s1, false);
            s2 = __builtin_amdgcn_fdot2(v2h, k10, s2, false);
            s3 = __builtin_amdgcn_fdot2(v2h, k01, s3, false);
            s0 = __builtin_amdgcn_fdot2(v3l, k10, s0, false);
            s1 = __builtin_amdgcn_fdot2(v3l, k01, s1, false);
            s2 = __builtin_amdgcn_fdot2(v3h, k10, s2, false);
            s3 = __builtin_amdgcn_fdot2(v3h, k01, s3, false);
        }
        float inv = 1.0f / fmaxf((float)deg, 1.0f);
        float4 rv = *(const float4*)&r1[(size_t)node * HID + q * 4];
        sh[nl * 17 + q * 4 + 0] = fmaxf(fmaf(s0, inv, rv.x), 0.f);
        sh[nl * 17 + q * 4 + 1] = fmaxf(fmaf(s1, inv, rv.y), 0.f);
        sh[nl * 17 + q * 4 + 2] = fmaxf(fmaf(s2, inv, rv.z), 0.f);
        sh[nl * 17 + q * 4 + 3] = fmaxf(fmaf(s3, inv, rv.w), 0.f);
    }
    __syncthreads();

    const float* hrow = &sh[nl * 17];
    if (q < 2) {
        int ob = q * 4;
        if (real) {
            float a0 = 0.f, a1 = 0.f, a2 = 0.f, a3 = 0.f;
#pragma unroll
            for (int k = 0; k < HID; ++k) {
                float hv = hrow[k];
                a0 = fmaf(hv, sW2l[k * OUTC + ob + 0], a0);
                a1 = fmaf(hv, sW2l[k * OUTC + ob + 1], a1);
                a2 = fmaf(hv, sW2l[k * OUTC + ob + 2], a2);
                a3 = fmaf(hv, sW2l[k * OUTC + ob + 3], a3);
            }
            half4_t o;
            o.x = (_Float16)a0; o.y = (_Float16)a1;
            o.z = (_Float16)a2; o.w = (_Float16)a3;
            *(half4_t*)(y2h + (size_t)node * OUTC + ob) = o;
        } else if (node == n_nodes) {
            half4_t z = {(_Float16)0.f, (_Float16)0.f, (_Float16)0.f, (_Float16)0.f};
            *(half4_t*)(y2h + (size_t)node * OUTC + ob) = z;   // sentinel row
        }
    } else if (real) {
        int ob = (q - 2) * 4;
        float a0 = sb2[ob + 0], a1 = sb2[ob + 1];
        float a2 = sb2[ob + 2], a3 = sb2[ob + 3];
#pragma unroll
        for (int k = 0; k < HID; ++k) {
            float hv = hrow[k];
            a0 = fmaf(hv, sW2r[k * OUTC + ob + 0], a0);
            a1 = fmaf(hv, sW2r[k * OUTC + ob + 1], a1);
            a2 = fmaf(hv, sW2r[k * OUTC + ob + 2], a2);
            a3 = fmaf(hv, sW2r[k * OUTC + ob + 3], a3);
        }
        float4 o = {a0, a1, a2, a3};
        *(float4*)(r2out + (size_t)node * OUTC + ob) = o;
    }
}

// ---------------------------------------------------------------------------
// K7: final gather. 2 threads/node, 128 nodes/block.
// ---------------------------------------------------------------------------
__global__ __launch_bounds__(256) void gather_out(
    const _Float16* __restrict__ y2h,
    const int*   __restrict__ off,
    const int*   __restrict__ cnt,
    const unsigned short* __restrict__ adj,
    float* __restrict__ out,
    int n_nodes)
{
    int tid = threadIdx.x;
    int node = blockIdx.x * 128 + (tid >> 1);
    if (node >= n_nodes) return;
    int r = tid & 1;

    int start = off[node];
    int deg   = cnt[node];
    int iters = (deg + 3) >> 2;
    const _Float16* yq = y2h + r * 4;
    const ushort4* ap = (const ushort4*)(adj + start);

    const half2_t k10 = {(_Float16)1.f, (_Float16)0.f};
    const half2_t k01 = {(_Float16)0.f, (_Float16)1.f};

    float s0 = 0.f, s1 = 0.f, s2 = 0.f, s3 = 0.f;
    for (int it = 0; it < iters; ++it) {
        ushort4 s = ap[it];
        half4_t v0 = *(const half4_t*)(yq + (size_t)s.x * OUTC);
        half4_t v1 = *(const half4_t*)(yq + (size_t)s.y * OUTC);
        half4_t v2 = *(const half4_t*)(yq + (size_t)s.z * OUTC);
        half4_t v3 = *(const half4_t*)(yq + (size_t)s.w * OUTC);
        half2_t v0l = {v0.x, v0.y}, v0h = {v0.z, v0.w};
        half2_t v1l = {v1.x, v1.y}, v1h = {v1.z, v1.w};
        half2_t v2l = {v2.x, v2.y}, v2h = {v2.z, v2.w};
        half2_t v3l = {v3.x, v3.y}, v3h = {v3.z, v3.w};
        s0 = __builtin_amdgcn_fdot2(v0l, k10, s0, false);
        s1 = __builtin_amdgcn_fdot2(v0l, k01, s1, false);
        s2 = __builtin_amdgcn_fdot2(v0h, k10, s2, false);
        s3 = __builtin_amdgcn_fdot2(v0h, k01, s3, false);
        s0 = __builtin_amdgcn_fdot2(v1l, k10, s0, false);
        s1 = __builtin_amdgcn_fdot2(v1l, k01, s1, false);
        s2 = __builtin_amdgcn_fdot2(v1h, k10, s2, false);
        s3 = __builtin_amdgcn_fdot2(v1h, k01, s3, false);
        s0 = __builtin_amdgcn_fdot2(v2l, k10, s0, false);
        s1 = __builtin_amdgcn_fdot2(v2l, k01, s1, false);
        s2 = __builtin_amdgcn_fdot2(v2h, k10, s2, false);
        s3 = __builtin_amdgcn_fdot2(v2h, k01, s3, false);
        s0 = __builtin_amdgcn_fdot2(v3l, k10, s0, false);
        s1 = __builtin_amdgcn_fdot2(v3l, k01, s1, false);
        s2 = __builtin_amdgcn_fdot2(v3h, k10, s2, false);
        s3 = __builtin_amdgcn_fdot2(v3h, k01, s3, false);
    }
    float inv = 1.0f / fmaxf((float)deg, 1.0f);

    float4* op = (float4*)(out + (size_t)node * OUTC + r * 4);
    float4 cv = *op;
    cv.x = fmaf(s0, inv, cv.x);
    cv.y = fmaf(s1, inv, cv.y);
    cv.z = fmaf(s2, inv, cv.z);
    cv.w = fmaf(s3, inv, cv.w);
    *op = cv;
}

extern "C" void kernel_launch(void* const* d_in, const int* in_sizes, int n_in,
                              void* d_out, int out_size, void* d_ws, size_t ws_size,
                              hipStream_t stream)
{
    const float* x   = (const float*)d_in[0];
    const float* W1l = (const float*)d_in[1];
    const float* W1r = (const float*)d_in[2];
    const float* b1  = (const float*)d_in[3];
    const float* W2l = (const float*)d_in[4];
    const float* W2r = (const float*)d_in[5];
    const float* b2  = (const float*)d_in[6];
    const int*   ei  = (const int*)d_in[7];

    int n_nodes = in_sizes[0] / IN_CH;       // 50000 (< 65535 for u16 + sentinel)
    int n_edges = in_sizes[7] / 2;           // 800000
    const int* esrc = ei;
    const int* edst = ei + n_edges;

    float* out = (float*)d_out;

    // ws layout (see header comment) — ~7.9 MB
    char* wsb = (char*)d_ws;
    _Float16* y1h = (_Float16*)wsb;                              // (N+1)*16 f16
    _Float16* y2h = y1h + (size_t)(n_nodes + 1) * HID;           // (N+1)*8 f16
    float* r1 = (float*)(y2h + (size_t)(n_nodes + 1) * OUTC);    // N*16 f32
    int* off  = (int*)(r1 + (size_t)n_nodes * HID);              // N i32
    int* cnt  = off + n_nodes;                                   // N i32
    int* cur  = cnt + n_nodes;                                   // N i32
    int* bsum = cur + n_nodes;                                   // 256 i32
    unsigned short* adj = (unsigned short*)(bsum + 256);         // E + 4N u16

    dim3 blk(256);
    int nb_edge = (n_edges + 255) / 256;                         // 3125
    int nb_scan = (n_nodes + 255) / 256;                         // 196 (<=256 req'd)

    // zero cnt + cur (contiguous)
    hipMemsetAsync(cnt, 0, (size_t)2 * n_nodes * sizeof(int), stream);

    xform1<<<dim3((n_nodes + 1 + 15) / 16), blk, 0, stream>>>(
        x, W1l, W1r, b1, y1h, r1, n_nodes);

    count_deg<<<dim3(nb_edge), blk, 0, stream>>>(edst, cnt, n_edges);

    scan_partials<<<dim3(nb_scan), blk, 0, stream>>>(cnt, bsum, n_nodes);
    scan_scatter<<<dim3(nb_scan), blk, 0, stream>>>(
        cnt, bsum, off, adj, n_nodes, nb_scan, n_nodes);

    fill_adj<<<dim3(nb_edge), blk, 0, stream>>>(
        esrc, edst, off, cur, adj, n_edges);

    fused_gather<<<dim3((n_nodes + 1 + 63) / 64), blk, 0, stream>>>(
        r1, y1h, off, cnt, adj, W2l, W2r, b2, y2h, out, n_nodes);

    gather_out<<<dim3((n_nodes + 127) / 128), blk, 0, stream>>>(
        y2h, off, cnt, adj, out, n_nodes);
}

// Round 9
// 139.533 us; speedup vs baseline: 1.3192x; 1.3192x over previous
//
#include <hip/hip_runtime.h>

#define IN_CH 64
#define HID   16
#define OUTC  8
#define BINSHIFT 6          // 64 slots/node bin (128 B = 2 lines). max deg ~45.
#define BINCAP  (1 << BINSHIFT)

typedef _Float16 half2_t __attribute__((ext_vector_type(2)));
typedef _Float16 half4_t __attribute__((ext_vector_type(4)));

// ---------------------------------------------------------------------------
// Workspace (~11 MB of the ~256 MB ws):
//   y1h : N*16 f16       layer-1 projected features (x @ W1l^T)
//   y2h : N*8  f16       layer-2 projected messages
//   r1  : N*16 f32       x @ W1r^T + b1
//   cur : N i32          per-node fill cursor == in-degree (memset 0)
//   adj : N*64 u16       binned CSR, bin n = adj[n<<6 ..]; no padding —
//                        gathers do 4-wide ushort4 iters + 0..3 scalar tail.
// Round-7/8 lessons baked in: binned fill (no count/scan passes) beats compact
// CSR; bins shrunk 256->64 slots to cut flush writeback (44.7 MB @ ~900 GB/s
// was the round-7 fill cost); fill overlapped with xform1 via block-range
// split (fill waves are 0.4% VALUBusy -> free issue slots).
// ---------------------------------------------------------------------------

// ---- K1: fused edge-bin fill + layer-1 dual projection --------------------
// blocks [0, nb_edge): scatter edges into bins (atomic cursor, no barriers)
// blocks [nb_edge, nb_edge+nb_node): 16 nodes x 16 ch projection
__global__ __launch_bounds__(256) void build_xform(
    const float* __restrict__ x,
    const int*   __restrict__ esrc,
    const int*   __restrict__ edst,
    const float* __restrict__ W1l,
    const float* __restrict__ W1r,
    const float* __restrict__ b1,
    int* __restrict__ cur,
    unsigned short* __restrict__ adj,
    _Float16* __restrict__ y1h,
    float* __restrict__ r1,
    int n_nodes, int n_edges, int nb_edge)
{
    __shared__ __align__(16) float sWl[HID * 68];   // [c][k] pad 68
    __shared__ __align__(16) float sWr[HID * 68];
    __shared__ __align__(16) float sx[16 * 68];     // staged x rows
    __shared__ float sb1[HID];

    int b   = blockIdx.x;
    int tid = threadIdx.x;

    if (b < nb_edge) {
        // ---- fill part: no barriers, latency-bound, ~idle issue slots ----
        int e = b * 256 + tid;
        if (e < n_edges) {
            int d = edst[e];
            int pos = atomicAdd(&cur[d], 1);
            if (pos < BINCAP)                        // safety guard
                adj[((size_t)d << BINSHIFT) + pos] = (unsigned short)esrc[e];
        }
        return;
    }

    // ---- projection part ----
    for (int i = tid; i < HID * IN_CH; i += 256) {
        int c = i >> 6, k = i & 63;                 // W1* is [HID][IN_CH]
        sWl[c * 68 + k] = W1l[i];
        sWr[c * 68 + k] = W1r[i];
    }
    if (tid < HID) sb1[tid] = b1[tid];

    int nl   = tid >> 4;
    int c    = tid & 15;
    int node = (b - nb_edge) * 16 + nl;

    if (node < n_nodes)
        *(float4*)&sx[nl * 68 + c * 4] =
            *(const float4*)&x[(size_t)node * IN_CH + c * 4];
    __syncthreads();
    if (node >= n_nodes) return;

    float accL = 0.f, accR = 0.f;
#pragma unroll
    for (int k4 = 0; k4 < 16; ++k4) {
        float4 xv = *(const float4*)&sx [nl * 68 + k4 * 4];
        float4 wl = *(const float4*)&sWl[c  * 68 + k4 * 4];
        float4 wr = *(const float4*)&sWr[c  * 68 + k4 * 4];
        accL = fmaf(xv.x, wl.x, accL); accL = fmaf(xv.y, wl.y, accL);
        accL = fmaf(xv.z, wl.z, accL); accL = fmaf(xv.w, wl.w, accL);
        accR = fmaf(xv.x, wr.x, accR); accR = fmaf(xv.y, wr.y, accR);
        accR = fmaf(xv.z, wr.z, accR); accR = fmaf(xv.w, wr.w, accR);
    }
    y1h[(size_t)node * HID + c] = (_Float16)accL;
    r1 [(size_t)node * HID + c] = accR + sb1[c];
}

// ---------------------------------------------------------------------------
// K2: fused gather + layer-2. 4 threads/node (q = channel quad), 64 nodes/blk.
//   sum4 = sum of y1h[adj] (ushort4 quads + 0..3 scalar tail, fdot2 acc)
//   h    = relu(sum4/deg + r1) -> LDS
//   q<2 : y2h = h @ W2l^T (f16) ; q>=2 : out = h @ W2r^T + b2
// ---------------------------------------------------------------------------
__global__ __launch_bounds__(256) void fused_gather(
    const float* __restrict__ r1,
    const _Float16* __restrict__ y1h,
    const int*   __restrict__ cur,
    const unsigned short* __restrict__ adj,
    const float* __restrict__ W2l, const float* __restrict__ W2r,
    const float* __restrict__ b2,
    _Float16* __restrict__ y2h, float* __restrict__ r2out,
    int n_nodes)
{
    __shared__ float sW2l[HID * OUTC];              // [k][o]
    __shared__ float sW2r[HID * OUTC];
    __shared__ float sb2[OUTC];
    __shared__ float sh[64 * 17];

    int tid = threadIdx.x;
    for (int i = tid; i < HID * OUTC; i += 256) {
        int o = i >> 4, k = i & 15;   // W2* is [OUTC][HID]
        sW2l[k * OUTC + o] = W2l[i];
        sW2r[k * OUTC + o] = W2r[i];
    }
    if (tid < OUTC) sb2[tid] = b2[tid];

    int nl   = tid >> 2;
    int q    = tid & 3;
    int node = blockIdx.x * 64 + nl;
    bool real = node < n_nodes;

    const half2_t k10 = {(_Float16)1.f, (_Float16)0.f};
    const half2_t k01 = {(_Float16)0.f, (_Float16)1.f};

    if (real) {
        int deg = cur[node];
        if (deg > BINCAP) deg = BINCAP;
        int iters = deg >> 2;
        float s0 = 0.f, s1 = 0.f, s2 = 0.f, s3 = 0.f;
        const _Float16* yq = y1h + q * 4;
        const unsigned short* row = adj + ((size_t)node << BINSHIFT);
        const ushort4* ap = (const ushort4*)row;
        for (int it = 0; it < iters; ++it) {
            ushort4 s = ap[it];
            half4_t v0 = *(const half4_t*)(yq + (size_t)s.x * HID);
            half4_t v1 = *(const half4_t*)(yq + (size_t)s.y * HID);
            half4_t v2 = *(const half4_t*)(yq + (size_t)s.z * HID);
            half4_t v3 = *(const half4_t*)(yq + (size_t)s.w * HID);
            half2_t v0l = {v0.x, v0.y}, v0h = {v0.z, v0.w};
            half2_t v1l = {v1.x, v1.y}, v1h = {v1.z, v1.w};
            half2_t v2l = {v2.x, v2.y}, v2h = {v2.z, v2.w};
            half2_t v3l = {v3.x, v3.y}, v3h = {v3.z, v3.w};
            s0 = __builtin_amdgcn_fdot2(v0l, k10, s0, false);
            s1 = __builtin_amdgcn_fdot2(v0l, k01, s1, false);
            s2 = __builtin_amdgcn_fdot2(v0h, k10, s2, false);
            s3 = __builtin_amdgcn_fdot2(v0h, k01, s3, false);
            s0 = __builtin_amdgcn_fdot2(v1l, k10, s0, false);
            s1 = __builtin_amdgcn_fdot2(v1l, k01, s1, false);
            s2 = __builtin_amdgcn_fdot2(v1h, k10, s2, false);
            s3 = __builtin_amdgcn_fdot2(v1h, k01, s3, false);
            s0 = __builtin_amdgcn_fdot2(v2l, k10, s0, false);
            s1 = __builtin_amdgcn_fdot2(v2l, k01, s1, false);
            s2 = __builtin_amdgcn_fdot2(v2h, k10, s2, false);
            s3 = __builtin_amdgcn_fdot2(v2h, k01, s3, false);
            s0 = __builtin_amdgcn_fdot2(v3l, k10, s0, false);
            s1 = __builtin_amdgcn_fdot2(v3l, k01, s1, false);
            s2 = __builtin_amdgcn_fdot2(v3h, k10, s2, false);
            s3 = __builtin_amdgcn_fdot2(v3h, k01, s3, false);
        }
        for (int g = iters << 2; g < deg; ++g) {    // 0..3 tail edges
            half4_t v = *(const half4_t*)(yq + (size_t)row[g] * HID);
            half2_t vl = {v.x, v.y}, vh = {v.z, v.w};
            s0 = __builtin_amdgcn_fdot2(vl, k10, s0, false);
            s1 = __builtin_amdgcn_fdot2(vl, k01, s1, false);
            s2 = __builtin_amdgcn_fdot2(vh, k10, s2, false);
            s3 = __builtin_amdgcn_fdot2(vh, k01, s3, false);
        }
        float inv = 1.0f / fmaxf((float)deg, 1.0f);
        float4 rv = *(const float4*)&r1[(size_t)node * HID + q * 4];
        sh[nl * 17 + q * 4 + 0] = fmaxf(fmaf(s0, inv, rv.x), 0.f);
        sh[nl * 17 + q * 4 + 1] = fmaxf(fmaf(s1, inv, rv.y), 0.f);
        sh[nl * 17 + q * 4 + 2] = fmaxf(fmaf(s2, inv, rv.z), 0.f);
        sh[nl * 17 + q * 4 + 3] = fmaxf(fmaf(s3, inv, rv.w), 0.f);
    }
    __syncthreads();
    if (!real) return;

    const float* hrow = &sh[nl * 17];
    if (q < 2) {
        int ob = q * 4;
        float a0 = 0.f, a1 = 0.f, a2 = 0.f, a3 = 0.f;
#pragma unroll
        for (int k = 0; k < HID; ++k) {
            float hv = hrow[k];
            a0 = fmaf(hv, sW2l[k * OUTC + ob + 0], a0);
            a1 = fmaf(hv, sW2l[k * OUTC + ob + 1], a1);
            a2 = fmaf(hv, sW2l[k * OUTC + ob + 2], a2);
            a3 = fmaf(hv, sW2l[k * OUTC + ob + 3], a3);
        }
        half4_t o;
        o.x = (_Float16)a0; o.y = (_Float16)a1;
        o.z = (_Float16)a2; o.w = (_Float16)a3;
        *(half4_t*)(y2h + (size_t)node * OUTC + ob) = o;
    } else {
        int ob = (q - 2) * 4;
        float a0 = sb2[ob + 0], a1 = sb2[ob + 1];
        float a2 = sb2[ob + 2], a3 = sb2[ob + 3];
#pragma unroll
        for (int k = 0; k < HID; ++k) {
            float hv = hrow[k];
            a0 = fmaf(hv, sW2r[k * OUTC + ob + 0], a0);
            a1 = fmaf(hv, sW2r[k * OUTC + ob + 1], a1);
            a2 = fmaf(hv, sW2r[k * OUTC + ob + 2], a2);
            a3 = fmaf(hv, sW2r[k * OUTC + ob + 3], a3);
        }
        float4 o = {a0, a1, a2, a3};
        *(float4*)(r2out + (size_t)node * OUTC + ob) = o;
    }
}

// ---------------------------------------------------------------------------
// K3: final gather. 2 threads/node, 128 nodes/block.
// out[node*8 + r*4..] = (sum of y2h[adj]) / deg + out  (out holds r2)
// ---------------------------------------------------------------------------
__global__ __launch_bounds__(256) void gather_out(
    const _Float16* __restrict__ y2h,
    const int*   __restrict__ cur,
    const unsigned short* __restrict__ adj,
    float* __restrict__ out,
    int n_nodes)
{
    int tid = threadIdx.x;
    int node = blockIdx.x * 128 + (tid >> 1);
    if (node >= n_nodes) return;
    int r = tid & 1;

    int deg = cur[node];
    if (deg > BINCAP) deg = BINCAP;
    int iters = deg >> 2;
    const _Float16* yq = y2h + r * 4;
    const unsigned short* row = adj + ((size_t)node << BINSHIFT);
    const ushort4* ap = (const ushort4*)row;

    const half2_t k10 = {(_Float16)1.f, (_Float16)0.f};
    const half2_t k01 = {(_Float16)0.f, (_Float16)1.f};

    float s0 = 0.f, s1 = 0.f, s2 = 0.f, s3 = 0.f;
    for (int it = 0; it < iters; ++it) {
        ushort4 s = ap[it];
        half4_t v0 = *(const half4_t*)(yq + (size_t)s.x * OUTC);
        half4_t v1 = *(const half4_t*)(yq + (size_t)s.y * OUTC);
        half4_t v2 = *(const half4_t*)(yq + (size_t)s.z * OUTC);
        half4_t v3 = *(const half4_t*)(yq + (size_t)s.w * OUTC);
        half2_t v0l = {v0.x, v0.y}, v0h = {v0.z, v0.w};
        half2_t v1l = {v1.x, v1.y}, v1h = {v1.z, v1.w};
        half2_t v2l = {v2.x, v2.y}, v2h = {v2.z, v2.w};
        half2_t v3l = {v3.x, v3.y}, v3h = {v3.z, v3.w};
        s0 = __builtin_amdgcn_fdot2(v0l, k10, s0, false);
        s1 = __builtin_amdgcn_fdot2(v0l, k01, s1, false);
        s2 = __builtin_amdgcn_fdot2(v0h, k10, s2, false);
        s3 = __builtin_amdgcn_fdot2(v0h, k01, s3, false);
        s0 = __builtin_amdgcn_fdot2(v1l, k10, s0, false);
        s1 = __builtin_amdgcn_fdot2(v1l, k01, s1, false);
        s2 = __builtin_amdgcn_fdot2(v1h, k10, s2, false);
        s3 = __builtin_amdgcn_fdot2(v1h, k01, s3, false);
        s0 = __builtin_amdgcn_fdot2(v2l, k10, s0, false);
        s1 = __builtin_amdgcn_fdot2(v2l, k01, s1, false);
        s2 = __builtin_amdgcn_fdot2(v2h, k10, s2, false);
        s3 = __builtin_amdgcn_fdot2(v2h, k01, s3, false);
        s0 = __builtin_amdgcn_fdot2(v3l, k10, s0, false);
        s1 = __builtin_amdgcn_fdot2(v3l, k01, s1, false);
        s2 = __builtin_amdgcn_fdot2(v3h, k10, s2, false);
        s3 = __builtin_amdgcn_fdot2(v3h, k01, s3, false);
    }
    for (int g = iters << 2; g < deg; ++g) {        // 0..3 tail edges
        half4_t v = *(const half4_t*)(yq + (size_t)row[g] * OUTC);
        half2_t vl = {v.x, v.y}, vh = {v.z, v.w};
        s0 = __builtin_amdgcn_fdot2(vl, k10, s0, false);
        s1 = __builtin_amdgcn_fdot2(vl, k01, s1, false);
        s2 = __builtin_amdgcn_fdot2(vh, k10, s2, false);
        s3 = __builtin_amdgcn_fdot2(vh, k01, s3, false);
    }
    float inv = 1.0f / fmaxf((float)deg, 1.0f);

    float4* op = (float4*)(out + (size_t)node * OUTC + r * 4);
    float4 cv = *op;
    cv.x = fmaf(s0, inv, cv.x);
    cv.y = fmaf(s1, inv, cv.y);
    cv.z = fmaf(s2, inv, cv.z);
    cv.w = fmaf(s3, inv, cv.w);
    *op = cv;
}

extern "C" void kernel_launch(void* const* d_in, const int* in_sizes, int n_in,
                              void* d_out, int out_size, void* d_ws, size_t ws_size,
                              hipStream_t stream)
{
    const float* x   = (const float*)d_in[0];
    const float* W1l = (const float*)d_in[1];
    const float* W1r = (const float*)d_in[2];
    const float* b1  = (const float*)d_in[3];
    const float* W2l = (const float*)d_in[4];
    const float* W2r = (const float*)d_in[5];
    const float* b2  = (const float*)d_in[6];
    const int*   ei  = (const int*)d_in[7];

    int n_nodes = in_sizes[0] / IN_CH;       // 50000 (< 65536 for u16 adj)
    int n_edges = in_sizes[7] / 2;           // 800000
    const int* esrc = ei;
    const int* edst = ei + n_edges;

    float* out = (float*)d_out;

    // ws layout (see header comment) — ~11 MB
    char* wsb = (char*)d_ws;
    _Float16* y1h = (_Float16*)wsb;                              // N*16 f16
    _Float16* y2h = y1h + (size_t)n_nodes * HID;                 // N*8 f16
    float* r1 = (float*)(y2h + (size_t)n_nodes * OUTC);          // N*16 f32
    int* cur  = (int*)(r1 + (size_t)n_nodes * HID);              // N i32
    unsigned short* adj = (unsigned short*)(cur + n_nodes);      // N*64 u16

    dim3 blk(256);
    int nb_edge = (n_edges + 255) / 256;                         // 3125
    int nb_node = (n_nodes + 15) / 16;                           // 3125

    hipMemsetAsync(cur, 0, (size_t)n_nodes * sizeof(int), stream);

    build_xform<<<dim3(nb_edge + nb_node), blk, 0, stream>>>(
        x, esrc, edst, W1l, W1r, b1, cur, adj, y1h, r1,
        n_nodes, n_edges, nb_edge);

    fused_gather<<<dim3((n_nodes + 63) / 64), blk, 0, stream>>>(
        r1, y1h, cur, adj, W2l, W2r, b2, y2h, out, n_nodes);

    gather_out<<<dim3((n_nodes + 127) / 128), blk, 0, stream>>>(
        y2h, cur, adj, out, n_nodes);
}

// Round 10
// 135.713 us; speedup vs baseline: 1.3564x; 1.0281x over previous
//
#include <hip/hip_runtime.h>

#define IN_CH 64
#define HID   16
#define OUTC  8
#define BINSHIFT 6          // 64 slots/node bin (128 B). max deg ~45 (Binom(800k,1/50k)).
#define BINCAP  (1 << BINSHIFT)
#define CHUNK   2048        // edges per scatter chunk (8 x 256)

typedef _Float16 half2_t __attribute__((ext_vector_type(2)));
typedef _Float16 half4_t __attribute__((ext_vector_type(4)));

// ---------------------------------------------------------------------------
// Workspace (~11 MB of the ~256 MB ws):
//   y1h : N*16 f16       layer-1 projected features (x @ W1l^T)
//   y2h : N*8  f16       layer-2 projected messages
//   r1  : N*16 f32       x @ W1r^T + b1
//   cur : N i32          per-node fill cursor == in-degree (memset 0)
//   adj : N*64 u16       binned CSR (no count/scan, no padding)
//
// Round-9 lesson: scatter WRITE_SIZE ~= one 64B line-writeback PER STORE
// (~45 MB for 800k stores) because random edge order makes every bin line
// dirty in ~all 8 XCD L2s; each flushes its fragment. Fix here: DST-SLICED
// scatter — slice = blockIdx & 7 (~XCD via round-robin dispatch heuristic;
// correctness is slice-partition-exact, placement is perf-only). Each chunk
// is read by 8 blocks; each stores only its dst slice -> bin/cur lines are
// single-XCD dirty. Trades 8x sequential edst reads (~26 MB, cheap) for
// ~35 MB of random cross-XCD writeback (expensive).
// ---------------------------------------------------------------------------

// ---- K1: dst-sliced edge-bin fill + layer-1 dual projection ---------------
// blocks [0, nb_scatter): scatter (slice = b & 7, chunk = b >> 3)
// blocks [nb_scatter, +nb_node): 16 nodes x 16 ch projection
__global__ __launch_bounds__(256) void build_xform(
    const float* __restrict__ x,
    const int*   __restrict__ esrc,
    const int*   __restrict__ edst,
    const float* __restrict__ W1l,
    const float* __restrict__ W1r,
    const float* __restrict__ b1,
    int* __restrict__ cur,
    unsigned short* __restrict__ adj,
    _Float16* __restrict__ y1h,
    float* __restrict__ r1,
    int n_nodes, int n_edges, int nb_scatter)
{
    __shared__ __align__(16) float sWl[HID * 68];   // [c][k] pad 68
    __shared__ __align__(16) float sWr[HID * 68];
    __shared__ __align__(16) float sx[16 * 68];     // staged x rows
    __shared__ float sb1[HID];

    int b   = blockIdx.x;
    int tid = threadIdx.x;

    if (b < nb_scatter) {
        // ---- dst-sliced scatter: no barriers ----
        int slice = b & 7;
        int chunk = b >> 3;
        int lo = (int)(((long long)slice       * n_nodes) >> 3);
        int hi = (int)(((long long)(slice + 1) * n_nodes) >> 3);
        int base = chunk * CHUNK;
#pragma unroll
        for (int j = 0; j < CHUNK / 256; ++j) {
            int e = base + j * 256 + tid;
            if (e < n_edges) {
                int d = edst[e];
                if (d >= lo && d < hi) {
                    int pos = atomicAdd(&cur[d], 1);
                    if (pos < BINCAP)                // safety guard
                        adj[((size_t)d << BINSHIFT) + pos] =
                            (unsigned short)esrc[e];
                }
            }
        }
        return;
    }

    // ---- projection part ----
    for (int i = tid; i < HID * IN_CH; i += 256) {
        int c = i >> 6, k = i & 63;                 // W1* is [HID][IN_CH]
        sWl[c * 68 + k] = W1l[i];
        sWr[c * 68 + k] = W1r[i];
    }
    if (tid < HID) sb1[tid] = b1[tid];

    int nl   = tid >> 4;
    int c    = tid & 15;
    int node = (b - nb_scatter) * 16 + nl;

    if (node < n_nodes)
        *(float4*)&sx[nl * 68 + c * 4] =
            *(const float4*)&x[(size_t)node * IN_CH + c * 4];
    __syncthreads();
    if (node >= n_nodes) return;

    float accL = 0.f, accR = 0.f;
#pragma unroll
    for (int k4 = 0; k4 < 16; ++k4) {
        float4 xv = *(const float4*)&sx [nl * 68 + k4 * 4];
        float4 wl = *(const float4*)&sWl[c  * 68 + k4 * 4];
        float4 wr = *(const float4*)&sWr[c  * 68 + k4 * 4];
        accL = fmaf(xv.x, wl.x, accL); accL = fmaf(xv.y, wl.y, accL);
        accL = fmaf(xv.z, wl.z, accL); accL = fmaf(xv.w, wl.w, accL);
        accR = fmaf(xv.x, wr.x, accR); accR = fmaf(xv.y, wr.y, accR);
        accR = fmaf(xv.z, wr.z, accR); accR = fmaf(xv.w, wr.w, accR);
    }
    y1h[(size_t)node * HID + c] = (_Float16)accL;
    r1 [(size_t)node * HID + c] = accR + sb1[c];
}

// ---------------------------------------------------------------------------
// K2: fused gather + layer-2. 4 threads/node (q = channel quad), 64 nodes/blk.
//   sum4 = sum of y1h[adj] (ushort4 quads + 0..3 scalar tail, fdot2 acc)
//   h    = relu(sum4/deg + r1) -> LDS
//   q<2 : y2h = h @ W2l^T (f16) ; q>=2 : out = h @ W2r^T + b2
// ---------------------------------------------------------------------------
__global__ __launch_bounds__(256) void fused_gather(
    const float* __restrict__ r1,
    const _Float16* __restrict__ y1h,
    const int*   __restrict__ cur,
    const unsigned short* __restrict__ adj,
    const float* __restrict__ W2l, const float* __restrict__ W2r,
    const float* __restrict__ b2,
    _Float16* __restrict__ y2h, float* __restrict__ r2out,
    int n_nodes)
{
    __shared__ float sW2l[HID * OUTC];              // [k][o]
    __shared__ float sW2r[HID * OUTC];
    __shared__ float sb2[OUTC];
    __shared__ float sh[64 * 17];

    int tid = threadIdx.x;
    for (int i = tid; i < HID * OUTC; i += 256) {
        int o = i >> 4, k = i & 15;   // W2* is [OUTC][HID]
        sW2l[k * OUTC + o] = W2l[i];
        sW2r[k * OUTC + o] = W2r[i];
    }
    if (tid < OUTC) sb2[tid] = b2[tid];

    int nl   = tid >> 2;
    int q    = tid & 3;
    int node = blockIdx.x * 64 + nl;
    bool real = node < n_nodes;

    const half2_t k10 = {(_Float16)1.f, (_Float16)0.f};
    const half2_t k01 = {(_Float16)0.f, (_Float16)1.f};

    if (real) {
        int deg = cur[node];
        if (deg > BINCAP) deg = BINCAP;
        int iters = deg >> 2;
        float s0 = 0.f, s1 = 0.f, s2 = 0.f, s3 = 0.f;
        const _Float16* yq = y1h + q * 4;
        const unsigned short* row = adj + ((size_t)node << BINSHIFT);
        const ushort4* ap = (const ushort4*)row;
        for (int it = 0; it < iters; ++it) {
            ushort4 s = ap[it];
            half4_t v0 = *(const half4_t*)(yq + (size_t)s.x * HID);
            half4_t v1 = *(const half4_t*)(yq + (size_t)s.y * HID);
            half4_t v2 = *(const half4_t*)(yq + (size_t)s.z * HID);
            half4_t v3 = *(const half4_t*)(yq + (size_t)s.w * HID);
            half2_t v0l = {v0.x, v0.y}, v0h = {v0.z, v0.w};
            half2_t v1l = {v1.x, v1.y}, v1h = {v1.z, v1.w};
            half2_t v2l = {v2.x, v2.y}, v2h = {v2.z, v2.w};
            half2_t v3l = {v3.x, v3.y}, v3h = {v3.z, v3.w};
            s0 = __builtin_amdgcn_fdot2(v0l, k10, s0, false);
            s1 = __builtin_amdgcn_fdot2(v0l, k01, s1, false);
            s2 = __builtin_amdgcn_fdot2(v0h, k10, s2, false);
            s3 = __builtin_amdgcn_fdot2(v0h, k01, s3, false);
            s0 = __builtin_amdgcn_fdot2(v1l, k10, s0, false);
            s1 = __builtin_amdgcn_fdot2(v1l, k01, s1, false);
            s2 = __builtin_amdgcn_fdot2(v1h, k10, s2, false);
            s3 = __builtin_amdgcn_fdot2(v1h, k01, s3, false);
            s0 = __builtin_amdgcn_fdot2(v2l, k10, s0, false);
            s1 = __builtin_amdgcn_fdot2(v2l, k01, s1, false);
            s2 = __builtin_amdgcn_fdot2(v2h, k10, s2, false);
            s3 = __builtin_amdgcn_fdot2(v2h, k01, s3, false);
            s0 = __builtin_amdgcn_fdot2(v3l, k10, s0, false);
            s1 = __builtin_amdgcn_fdot2(v3l, k01, s1, false);
            s2 = __builtin_amdgcn_fdot2(v3h, k10, s2, false);
            s3 = __builtin_amdgcn_fdot2(v3h, k01, s3, false);
        }
        for (int g = iters << 2; g < deg; ++g) {    // 0..3 tail edges
            half4_t v = *(const half4_t*)(yq + (size_t)row[g] * HID);
            half2_t vl = {v.x, v.y}, vh = {v.z, v.w};
            s0 = __builtin_amdgcn_fdot2(vl, k10, s0, false);
            s1 = __builtin_amdgcn_fdot2(vl, k01, s1, false);
            s2 = __builtin_amdgcn_fdot2(vh, k10, s2, false);
            s3 = __builtin_amdgcn_fdot2(vh, k01, s3, false);
        }
        float inv = 1.0f / fmaxf((float)deg, 1.0f);
        float4 rv = *(const float4*)&r1[(size_t)node * HID + q * 4];
        sh[nl * 17 + q * 4 + 0] = fmaxf(fmaf(s0, inv, rv.x), 0.f);
        sh[nl * 17 + q * 4 + 1] = fmaxf(fmaf(s1, inv, rv.y), 0.f);
        sh[nl * 17 + q * 4 + 2] = fmaxf(fmaf(s2, inv, rv.z), 0.f);
        sh[nl * 17 + q * 4 + 3] = fmaxf(fmaf(s3, inv, rv.w), 0.f);
    }
    __syncthreads();
    if (!real) return;

    const float* hrow = &sh[nl * 17];
    if (q < 2) {
        int ob = q * 4;
        float a0 = 0.f, a1 = 0.f, a2 = 0.f, a3 = 0.f;
#pragma unroll
        for (int k = 0; k < HID; ++k) {
            float hv = hrow[k];
            a0 = fmaf(hv, sW2l[k * OUTC + ob + 0], a0);
            a1 = fmaf(hv, sW2l[k * OUTC + ob + 1], a1);
            a2 = fmaf(hv, sW2l[k * OUTC + ob + 2], a2);
            a3 = fmaf(hv, sW2l[k * OUTC + ob + 3], a3);
        }
        half4_t o;
        o.x = (_Float16)a0; o.y = (_Float16)a1;
        o.z = (_Float16)a2; o.w = (_Float16)a3;
        *(half4_t*)(y2h + (size_t)node * OUTC + ob) = o;
    } else {
        int ob = (q - 2) * 4;
        float a0 = sb2[ob + 0], a1 = sb2[ob + 1];
        float a2 = sb2[ob + 2], a3 = sb2[ob + 3];
#pragma unroll
        for (int k = 0; k < HID; ++k) {
            float hv = hrow[k];
            a0 = fmaf(hv, sW2r[k * OUTC + ob + 0], a0);
            a1 = fmaf(hv, sW2r[k * OUTC + ob + 1], a1);
            a2 = fmaf(hv, sW2r[k * OUTC + ob + 2], a2);
            a3 = fmaf(hv, sW2r[k * OUTC + ob + 3], a3);
        }
        float4 o = {a0, a1, a2, a3};
        *(float4*)(r2out + (size_t)node * OUTC + ob) = o;
    }
}

// ---------------------------------------------------------------------------
// K3: final gather. 2 threads/node, 128 nodes/block.
// out[node*8 + r*4..] = (sum of y2h[adj]) / deg + out  (out holds r2)
// ---------------------------------------------------------------------------
__global__ __launch_bounds__(256) void gather_out(
    const _Float16* __restrict__ y2h,
    const int*   __restrict__ cur,
    const unsigned short* __restrict__ adj,
    float* __restrict__ out,
    int n_nodes)
{
    int tid = threadIdx.x;
    int node = blockIdx.x * 128 + (tid >> 1);
    if (node >= n_nodes) return;
    int r = tid & 1;

    int deg = cur[node];
    if (deg > BINCAP) deg = BINCAP;
    int iters = deg >> 2;
    const _Float16* yq = y2h + r * 4;
    const unsigned short* row = adj + ((size_t)node << BINSHIFT);
    const ushort4* ap = (const ushort4*)row;

    const half2_t k10 = {(_Float16)1.f, (_Float16)0.f};
    const half2_t k01 = {(_Float16)0.f, (_Float16)1.f};

    float s0 = 0.f, s1 = 0.f, s2 = 0.f, s3 = 0.f;
    for (int it = 0; it < iters; ++it) {
        ushort4 s = ap[it];
        half4_t v0 = *(const half4_t*)(yq + (size_t)s.x * OUTC);
        half4_t v1 = *(const half4_t*)(yq + (size_t)s.y * OUTC);
        half4_t v2 = *(const half4_t*)(yq + (size_t)s.z * OUTC);
        half4_t v3 = *(const half4_t*)(yq + (size_t)s.w * OUTC);
        half2_t v0l = {v0.x, v0.y}, v0h = {v0.z, v0.w};
        half2_t v1l = {v1.x, v1.y}, v1h = {v1.z, v1.w};
        half2_t v2l = {v2.x, v2.y}, v2h = {v2.z, v2.w};
        half2_t v3l = {v3.x, v3.y}, v3h = {v3.z, v3.w};
        s0 = __builtin_amdgcn_fdot2(v0l, k10, s0, false);
        s1 = __builtin_amdgcn_fdot2(v0l, k01, s1, false);
        s2 = __builtin_amdgcn_fdot2(v0h, k10, s2, false);
        s3 = __builtin_amdgcn_fdot2(v0h, k01, s3, false);
        s0 = __builtin_amdgcn_fdot2(v1l, k10, s0, false);
        s1 = __builtin_amdgcn_fdot2(v1l, k01, s1, false);
        s2 = __builtin_amdgcn_fdot2(v1h, k10, s2, false);
        s3 = __builtin_amdgcn_fdot2(v1h, k01, s3, false);
        s0 = __builtin_amdgcn_fdot2(v2l, k10, s0, false);
        s1 = __builtin_amdgcn_fdot2(v2l, k01, s1, false);
        s2 = __builtin_amdgcn_fdot2(v2h, k10, s2, false);
        s3 = __builtin_amdgcn_fdot2(v2h, k01, s3, false);
        s0 = __builtin_amdgcn_fdot2(v3l, k10, s0, false);
        s1 = __builtin_amdgcn_fdot2(v3l, k01, s1, false);
        s2 = __builtin_amdgcn_fdot2(v3h, k10, s2, false);
        s3 = __builtin_amdgcn_fdot2(v3h, k01, s3, false);
    }
    for (int g = iters << 2; g < deg; ++g) {        // 0..3 tail edges
        half4_t v = *(const half4_t*)(yq + (size_t)row[g] * OUTC);
        half2_t vl = {v.x, v.y}, vh = {v.z, v.w};
        s0 = __builtin_amdgcn_fdot2(vl, k10, s0, false);
        s1 = __builtin_amdgcn_fdot2(vl, k01, s1, false);
        s2 = __builtin_amdgcn_fdot2(vh, k10, s2, false);
        s3 = __builtin_amdgcn_fdot2(vh, k01, s3, false);
    }
    float inv = 1.0f / fmaxf((float)deg, 1.0f);

    float4* op = (float4*)(out + (size_t)node * OUTC + r * 4);
    float4 cv = *op;
    cv.x = fmaf(s0, inv, cv.x);
    cv.y = fmaf(s1, inv, cv.y);
    cv.z = fmaf(s2, inv, cv.z);
    cv.w = fmaf(s3, inv, cv.w);
    *op = cv;
}

extern "C" void kernel_launch(void* const* d_in, const int* in_sizes, int n_in,
                              void* d_out, int out_size, void* d_ws, size_t ws_size,
                              hipStream_t stream)
{
    const float* x   = (const float*)d_in[0];
    const float* W1l = (const float*)d_in[1];
    const float* W1r = (const float*)d_in[2];
    const float* b1  = (const float*)d_in[3];
    const float* W2l = (const float*)d_in[4];
    const float* W2r = (const float*)d_in[5];
    const float* b2  = (const float*)d_in[6];
    const int*   ei  = (const int*)d_in[7];

    int n_nodes = in_sizes[0] / IN_CH;       // 50000 (< 65536 for u16 adj)
    int n_edges = in_sizes[7] / 2;           // 800000
    const int* esrc = ei;
    const int* edst = ei + n_edges;

    float* out = (float*)d_out;

    // ws layout (see header comment) — ~11 MB
    char* wsb = (char*)d_ws;
    _Float16* y1h = (_Float16*)wsb;                              // N*16 f16
    _Float16* y2h = y1h + (size_t)n_nodes * HID;                 // N*8 f16
    float* r1 = (float*)(y2h + (size_t)n_nodes * OUTC);          // N*16 f32
    int* cur  = (int*)(r1 + (size_t)n_nodes * HID);              // N i32
    unsigned short* adj = (unsigned short*)(cur + n_nodes);      // N*64 u16

    dim3 blk(256);
    int n_chunks   = (n_edges + CHUNK - 1) / CHUNK;              // 391
    int nb_scatter = n_chunks * 8;                               // 3128
    int nb_node    = (n_nodes + 15) / 16;                        // 3125

    hipMemsetAsync(cur, 0, (size_t)n_nodes * sizeof(int), stream);

    build_xform<<<dim3(nb_scatter + nb_node), blk, 0, stream>>>(
        x, esrc, edst, W1l, W1r, b1, cur, adj, y1h, r1,
        n_nodes, n_edges, nb_scatter);

    fused_gather<<<dim3((n_nodes + 63) / 64), blk, 0, stream>>>(
        r1, y1h, cur, adj, W2l, W2r, b2, y2h, out, n_nodes);

    gather_out<<<dim3((n_nodes + 127) / 128), blk, 0, stream>>>(
        y2h, cur, adj, out, n_nodes);
}